// Round 9
// baseline (458.955 us; speedup 1.0000x reference)
//
#include <hip/hip_runtime.h>
#include <cstdint>
#include <cstddef>

#define DEVINL __device__ __forceinline__

typedef __bf16 bf16x8 __attribute__((ext_vector_type(8)));
typedef float  f32x4  __attribute__((ext_vector_type(4)));

// ---------------- helpers ----------------

DEVINL unsigned short f2b(float f) {   // f32 -> bf16 bits, round-to-nearest-even
  unsigned u = __builtin_bit_cast(unsigned, f);
  u += 0x7fffu + ((u >> 16) & 1u);
  return (unsigned short)(u >> 16);
}

DEVINL unsigned packtrunc(float a, float b) {  // 2x f32 -> packed bf16 (truncate)
  unsigned ua = __builtin_bit_cast(unsigned, a);
  unsigned ub = __builtin_bit_cast(unsigned, b);
  return (ua >> 16) | (ub & 0xffff0000u);
}

DEVINL void async16(void* lds, const void* g) {
  __builtin_amdgcn_global_load_lds((const __attribute__((address_space(1))) unsigned*)g,
                                   (__attribute__((address_space(3))) unsigned*)lds,
                                   16, 0, 0);
}

// ---------------- fused weight f32 -> bf16 cast (all 4 weights, 1 launch) ----------------
// mlp_w1 rows INTERLEAVED: gate row i -> 2i, up row i -> 2i+1 (GLU via shfl_xor(1)).

__global__ void cvt4_kernel(const float* __restrict__ s0, const float* __restrict__ s1,
                            const float* __restrict__ s2, const float* __restrict__ s3,
                            unsigned short* __restrict__ d0, unsigned short* __restrict__ d1,
                            unsigned short* __restrict__ d2, unsigned short* __restrict__ d3) {
  int i = blockIdx.x * 256 + threadIdx.x;   // float4 index, total 4194304
  if (i < 786432) {
    float4 v = ((const float4*)s0)[i];
    ushort4 o; o.x = f2b(v.x); o.y = f2b(v.y); o.z = f2b(v.z); o.w = f2b(v.w);
    ((ushort4*)d0)[i] = o;
  } else if (i < 1048576) {
    int off = i - 786432;
    float4 v = ((const float4*)s1)[off];
    ushort4 o; o.x = f2b(v.x); o.y = f2b(v.y); o.z = f2b(v.z); o.w = f2b(v.w);
    ((ushort4*)d1)[off] = o;
  } else if (i < 3145728) {
    int off = i - 1048576;                  // mlp_w1: 8192 rows x 256 float4
    int row = off >> 8, col = off & 255;
    int rp = (row < 4096) ? (row << 1) : (((row - 4096) << 1) | 1);
    float4 v = ((const float4*)s2)[off];
    ushort4 o; o.x = f2b(v.x); o.y = f2b(v.y); o.z = f2b(v.z); o.w = f2b(v.w);
    ((ushort4*)d2)[rp * 256 + col] = o;
  } else {
    int off = i - 3145728;
    float4 v = ((const float4*)s3)[off];
    ushort4 o; o.x = f2b(v.x); o.y = f2b(v.y); o.z = f2b(v.z); o.w = f2b(v.w);
    ((ushort4*)d3)[off] = o;
  }
}

// ---------------- conditioning: silu(c) @ {shift,scale}_w^T + b ----------------

__global__ void cond_kernel(const float* __restrict__ c,
                            const float* __restrict__ scale_w, const float* __restrict__ scale_b,
                            const float* __restrict__ shift_w, const float* __restrict__ shift_b,
                            float* __restrict__ scale_o, float* __restrict__ shift_o) {
  __shared__ float sc[1024];
  __shared__ float red[2][4][64];
  int tid = threadIdx.x;
  int b = blockIdx.x >> 4, ch = blockIdx.x & 15;
  for (int i = tid; i < 1024; i += 256) {
    float cv = c[b * 1024 + i];
    sc[i] = cv / (1.f + __expf(-cv));
  }
  __syncthreads();
  int colidx = tid & 63, p = tid >> 6;
  int co = ch * 64 + colidx;
  float dsc = 0.f, dsh = 0.f;
  for (int i = 0; i < 256; ++i) {
    int kk = p * 256 + i;
    float s = sc[kk];
    dsc += s * scale_w[(size_t)co * 1024 + kk];
    dsh += s * shift_w[(size_t)co * 1024 + kk];
  }
  red[0][p][colidx] = dsc;
  red[1][p][colidx] = dsh;
  __syncthreads();
  if (p == 0) {
    float s4  = red[0][0][colidx] + red[0][1][colidx] + red[0][2][colidx] + red[0][3][colidx];
    float sh4 = red[1][0][colidx] + red[1][1][colidx] + red[1][2][colidx] + red[1][3][colidx];
    scale_o[b * 1024 + co] = fminf(fmaxf(s4 + scale_b[co] + 1.f, 0.1f), 10.f);
    shift_o[b * 1024 + co] = sh4 + shift_b[co];
  }
}

// ---------------- adaLN ----------------

__global__ __launch_bounds__(256) void adaln_kernel(const float* __restrict__ x,
                                                    const float* __restrict__ norm_w,
                                                    const float* __restrict__ scale,
                                                    const float* __restrict__ shift,
                                                    unsigned short* __restrict__ h) {
  int row = blockIdx.x;
  int b = row >> 11;
  int tid = threadIdx.x;
  float4 v = ((const float4*)(x + (size_t)row * 1024))[tid];
  float ss = v.x * v.x + v.y * v.y + v.z * v.z + v.w * v.w;
  #pragma unroll
  for (int d = 32; d; d >>= 1) ss += __shfl_xor(ss, d);
  __shared__ float wsum[4];
  if ((tid & 63) == 0) wsum[tid >> 6] = ss;
  __syncthreads();
  float tot = wsum[0] + wsum[1] + wsum[2] + wsum[3];
  float inv = 1.f / fmaxf(sqrtf(tot * (1.f / 1024.f)), 1e-6f);
  float4 nw  = ((const float4*)norm_w)[tid];
  float4 scv = ((const float4*)(scale + b * 1024))[tid];
  float4 shv = ((const float4*)(shift + b * 1024))[tid];
  ushort4 o;
  o.x = f2b(v.x * inv * nw.x * scv.x + shv.x);
  o.y = f2b(v.y * inv * nw.y * scv.y + shv.y);
  o.z = f2b(v.z * inv * nw.z * scv.z + shv.z);
  o.w = f2b(v.w * inv * nw.w * scv.w + shv.w);
  ((ushort4*)(h + (size_t)row * 1024))[tid] = o;
}

// ---------------- MT x 128 bf16 MFMA GEMM, BK=32 2-slot async ring:  C = A[M,K] @ B[N,K]^T ----
// ROUND-9: ring step shrunk BK=64 -> BK=32. Slot = A(MTx32) + B(128x32):
//   MT=64:  12 KB/slot, ring 24 KB -> 6 blk/CU (pre-ring occupancy RESTORED, ring kept)
//   MT=128: 16 KB/slot, ring 32 KB; EPI1 stage 34.8 KB is the max -> 4 blk/CU restored
// Per-step loads L = MT/64 + 2 async16/thread. Ledger: prologue stages steps 0,1;
// top-of-iter vmcnt(L) retires step s (s+1's L in flight, one compute phase of cover);
// lgkmcnt(0)+barrier gates refill of slot s&1 with step s+2; vmcnt(0) final step only.

template<int EPI, int MT>
__global__ __launch_bounds__(256, 1) void gemm_k(
    const unsigned short* __restrict__ A,
    const unsigned short* __restrict__ B0,
    const float* __restrict__ bias0,
    const float* __restrict__ resid,
    void* __restrict__ out0_, void* __restrict__ out1_, void* __restrict__ out2_,
    int M, int N, int K) {
  constexpr int MI = MT / 32;              // m-frags per wave
  constexpr int A_HALF = MT * 32;          // shorts: A panel of one BK=32 step
  constexpr int SLOT_SH = A_HALF + 4096;   // + B panel 128x32
  constexpr int RING_SH = 2 * SLOT_SH;
  constexpr int STAGE_SH = (EPI == 1) ? 128 * 136 : (EPI == 2 ? 128 * 72 : 0);
  constexpr int SMEM_SH = (RING_SH > STAGE_SH) ? RING_SH : STAGE_SH;
  __shared__ __align__(16) unsigned short smem[SMEM_SH];

  const int tid = threadIdx.x;
  const int wave = tid >> 6, lane = tid & 63;
  const int quad = lane >> 4, l16 = lane & 15;
  const int wm = (wave >> 1) * (MT / 2), wn = (wave & 1) * 64;
  const int bm = blockIdx.y * MT, bn = blockIdx.x * 128;

  f32x4 acc[MI][4] = {};
  const int steps = K >> 5;                // BK=32 steps

  // stage BK=32 step s into ring slot r (L = MT/64 + 2 async16 per thread)
  auto STAGE = [&](int s, int r) {
    const int k0 = s << 5;
    unsigned short* base = smem + r * SLOT_SH;
    #pragma unroll
    for (int i = 0; i < MT / 64; ++i) {
      int cc = i * 256 + tid;
      int rr = cc >> 2, ko = (cc & 3) << 3;
      size_t ga = (size_t)(bm + rr) * K + k0 + ko;
      async16(base + (i * 2048 + wave * 512), A + ga);
    }
    #pragma unroll
    for (int i = 0; i < 2; ++i) {
      int cc = i * 256 + tid;
      int rr = cc >> 2, ko = (cc & 3) << 3;
      size_t gb = (size_t)(bn + rr) * K + k0 + ko;
      async16(base + A_HALF + (i * 2048 + wave * 512), B0 + gb);
    }
  };

  // prologue: stage steps 0 and 1
  STAGE(0, 0);
  if (steps > 1) STAGE(1, 1);

  for (int s = 0; s < steps; ++s) {
    // retire step s: exactly step s+1's L loads may remain in flight
    if (s < steps - 1) {
      if constexpr (MT == 64) asm volatile("s_waitcnt vmcnt(3)" ::: "memory");
      else                    asm volatile("s_waitcnt vmcnt(4)" ::: "memory");
    } else {
      asm volatile("s_waitcnt vmcnt(0)" ::: "memory");
    }
    __builtin_amdgcn_s_barrier();

    const unsigned short* base = smem + (s & 1) * SLOT_SH;
    const unsigned short* Ah = base;
    const unsigned short* Bh = base + A_HALF;
    bf16x8 af[MI], bfr[4];
    #pragma unroll
    for (int mi = 0; mi < MI; ++mi)
      af[mi] = *reinterpret_cast<const bf16x8*>(&Ah[(wm + mi * 16 + l16) * 32 + quad * 8]);
    #pragma unroll
    for (int ni = 0; ni < 4; ++ni)
      bfr[ni] = *reinterpret_cast<const bf16x8*>(&Bh[(wn + ni * 16 + l16) * 32 + quad * 8]);
    #pragma unroll
    for (int mi = 0; mi < MI; ++mi)
      #pragma unroll
      for (int ni = 0; ni < 4; ++ni)
        acc[mi][ni] = __builtin_amdgcn_mfma_f32_16x16x32_bf16(af[mi], bfr[ni], acc[mi][ni], 0, 0, 0);

    // all waves done reading slot s&1, then refill it with step s+2
    asm volatile("s_waitcnt lgkmcnt(0)" ::: "memory");
    __builtin_amdgcn_s_barrier();
    if (s + 2 < steps) STAGE(s + 2, s & 1);
  }
  // final iter drained vmcnt(0) at top and issued nothing after -> smem reusable.

  // ---------- epilogue: C/D layout col=lane&15, row=quad*4+reg ----------
  if constexpr (EPI == 0) {
    #pragma unroll
    for (int mi = 0; mi < MI; ++mi) {
      #pragma unroll
      for (int ni = 0; ni < 4; ++ni) {
        int gc = bn + wn + ni * 16 + l16;
        #pragma unroll
        for (int r = 0; r < 4; ++r) {
          int gr = bm + wm + mi * 16 + quad * 4 + r;
          ((float*)out0_)[(size_t)gr * N + gc] = acc[mi][ni][r] + bias0[gc] + resid[(size_t)gr * N + gc];
        }
      }
    }
  } else if constexpr (EPI == 1) {
    const int region = bn >> 10;          // 0=q, 1=k, 2=v
    __syncthreads();
    #pragma unroll
    for (int mi = 0; mi < MI; ++mi) {
      #pragma unroll
      for (int ni = 0; ni < 4; ++ni) {
        int lc = wn + ni * 16 + l16;
        #pragma unroll
        for (int r = 0; r < 4; ++r) {
          int lr = wm + mi * 16 + quad * 4 + r;
          float v = acc[mi][ni][r];
          if (region == 0)      smem[lr * 136 + lc] = f2b(v * 0.125f);
          else if (region == 1) smem[lr * 136 + lc] = f2b(v);
          else                  smem[lc * 136 + lr] = f2b(v);   // transpose for v
        }
      }
    }
    __syncthreads();
    const int b = bm >> 11;
    const int bnm = bn & 1023;
    if (region <= 1) {
      int lr = tid >> 1, hl = tid & 1;
      int n = (bm + lr) & 2047;
      int hh = (bnm >> 6) + hl;
      unsigned short* dst = (unsigned short*)(region == 0 ? out0_ : out1_) +
                            (((size_t)(b * 16 + hh)) * 2048 + n) * 64;
      const unsigned short* src = smem + lr * 136 + hl * 64;
      #pragma unroll
      for (int j = 0; j < 8; ++j)
        ((uint4*)dst)[j] = *(const uint4*)(src + j * 8);
    } else {
      int lc = tid >> 1, nh = tid & 1;
      int c2 = bnm + lc;
      int hh = c2 >> 6, d = c2 & 63;
      int nbase = (bm & 2047) + nh * 64;
      unsigned short* dst = (unsigned short*)out2_ +
                            (((size_t)(b * 16 + hh)) * 64 + d) * 2048 + nbase;
      const unsigned short* src = smem + lc * 136 + nh * 64;
      #pragma unroll
      for (int j = 0; j < 8; ++j)
        ((uint4*)dst)[j] = *(const uint4*)(src + j * 8);
    }
  } else {   // EPI 2: interleaved GLU -> bf16 [M, N/2]
    __syncthreads();
    #pragma unroll
    for (int mi = 0; mi < MI; ++mi) {
      #pragma unroll
      for (int ni = 0; ni < 4; ++ni) {
        int lc = wn + ni * 16 + l16;
        int gcp = bn + lc;
        int gi = gcp >> 1;
        float bias = bias0[(gcp & 1) ? 4096 + gi : gi];
        #pragma unroll
        for (int r = 0; r < 4; ++r) {
          int lr = wm + mi * 16 + quad * 4 + r;
          float v = acc[mi][ni][r] + bias;
          float p = __shfl_xor(v, 1);
          if ((l16 & 1) == 0) {
            float g = (v / (1.f + __expf(-v))) * p;
            smem[lr * 72 + (lc >> 1)] = f2b(g);
          }
        }
      }
    }
    __syncthreads();
    int lr = tid >> 1, ch = (tid & 1) * 32;
    unsigned short* dst = (unsigned short*)out0_ + (size_t)(bm + lr) * (N >> 1) + (bn >> 1) + ch;
    const unsigned short* src = smem + lr * 72 + ch;
    #pragma unroll
    for (int j = 0; j < 4; ++j)
      ((uint4*)dst)[j] = *(const uint4*)(src + j * 8);
  }
}

// ---------------- 256x256 bf16 MFMA GEMM, 8-phase schedule + XCD column-ownership ----------------
// C = A[M,K] @ B[N,K]^T, fused interleaved-GLU epilogue -> bf16 [M, N/2].
// XCD x owns bx in {4x..4x+3} (2 MiB B, L2-resident); FETCH_SIZE verified 135->49 MB.
// Pinned at ~667 TF across 3 schedules x 2 mappings (lockstep at 1 blk/CU). Structural.

__global__ __launch_bounds__(512, 2) void gemm256_glu(
    const unsigned short* __restrict__ A,
    const unsigned short* __restrict__ B,
    const float* __restrict__ bias,
    unsigned short* __restrict__ out,
    int M, int N, int K) {
  // shorts: [0,16384) A buf0 | [16384,32768) A buf1 | [32768,49152) B buf0 | [49152,65536) B buf1
  __shared__ __align__(16) unsigned short smem[65536];   // 128 KiB

  const int tid  = threadIdx.x;
  const int wave = tid >> 6, lane = tid & 63;
  const int quad = lane >> 4, l16 = lane & 15;
  const int wm = (wave >> 2) * 128, wn = (wave & 3) * 64;

  // XCD column-ownership mapping. Grid is exactly (32,16).
  const int lin = blockIdx.y * gridDim.x + blockIdx.x;
  const int xcd = lin & 7, idx = lin >> 3;     // idx in [0,64)
  const int bx = (xcd << 2) + (idx & 3);       // [0,32): 4 N-panels per XCD
  const int by = idx >> 2;                     // [0,16)
  const int bm = by * 256, bn = bx * 256;

  // staging: thread covers 2 chunks per half-tile (rows tid>>3 and +64),
  // same swizzled k-chunk for both (row&7 identical). Linear LDS dest.
  const int srow = tid >> 3;
  const int slc  = (tid & 7) ^ (srow & 7);
  const unsigned short* gA0 = A + (size_t)(bm + srow) * K + slc * 8;
  const unsigned short* gB0 = B + (size_t)(bn + srow) * K + slc * 8;
  const size_t rstep = (size_t)64 * K;

#define STAGE_A(h, tk, d) do { \
    const unsigned short* s_ = gA0 + (size_t)(h) * 128 * K + (size_t)(tk) * 64; \
    async16(smem + (d) * 16384 + (h) * 8192 + tid * 8, s_); \
    async16(smem + (d) * 16384 + (h) * 8192 + 4096 + tid * 8, s_ + rstep); \
  } while (0)
#define STAGE_B(h, tk, d) do { \
    const unsigned short* s_ = gB0 + (size_t)(h) * 128 * K + (size_t)(tk) * 64; \
    async16(smem + 32768 + (d) * 16384 + (h) * 8192 + tid * 8, s_); \
    async16(smem + 32768 + (d) * 16384 + (h) * 8192 + 4096 + tid * 8, s_ + rstep); \
  } while (0)

  const int pc0 = (quad ^ (l16 & 7)) * 8;         // swizzled chunk offset, k-half 0
  const int pc1 = ((quad + 4) ^ (l16 & 7)) * 8;   // k-half 1
  const int arow = wm + l16;
  const int brow = wn + l16;

  f32x4 acc[8][4] = {};
  bf16x8 bfr[4][2];
  const int T = K >> 6;        // 16 K-tiles
  const int JI = T >> 1;       // 8 iterations, 2 tiles each

  // ---- prologue: t0.B, t0.A -> buf0; t1.B -> buf1 (t1.B issued LAST) ----
  STAGE_B(0, 0, 0); STAGE_B(1, 0, 0);
  STAGE_A(0, 0, 0); STAGE_A(1, 0, 0);
  STAGE_B(0, 1, 1); STAGE_B(1, 1, 1);
  asm volatile("s_waitcnt vmcnt(4)" ::: "memory");   // tile-0 (8 oldest) landed
  __builtin_amdgcn_s_barrier();

#define READ_BFR(d) do { \
    _Pragma("unroll") \
    for (int ni = 0; ni < 4; ++ni) { \
      int rb = 32768 + (d) * 16384 + (brow + ni * 16) * 64; \
      bfr[ni][0] = *reinterpret_cast<const bf16x8*>(&smem[rb + pc0]); \
      bfr[ni][1] = *reinterpret_cast<const bf16x8*>(&smem[rb + pc1]); \
    } \
  } while (0)

#define PHASE(d, q, RB, STAGE_STMT, TAIL_STMT) do { \
    bf16x8 a00, a01, a10, a11; \
    if (RB) READ_BFR(d); \
    { int ra = (d) * 16384 + (arow + (2 * (q)) * 16) * 64; \
      a00 = *reinterpret_cast<const bf16x8*>(&smem[ra + pc0]); \
      a01 = *reinterpret_cast<const bf16x8*>(&smem[ra + pc1]); \
      a10 = *reinterpret_cast<const bf16x8*>(&smem[ra + 1024 + pc0]); \
      a11 = *reinterpret_cast<const bf16x8*>(&smem[ra + 1024 + pc1]); } \
    STAGE_STMT; \
    if (RB) asm volatile("s_waitcnt lgkmcnt(8)" ::: "memory"); \
    __builtin_amdgcn_s_barrier(); \
    asm volatile("s_waitcnt lgkmcnt(0)" ::: "memory"); \
    __builtin_amdgcn_sched_barrier(0); \
    __builtin_amdgcn_s_setprio(1); \
    _Pragma("unroll") \
    for (int ni = 0; ni < 4; ++ni) \
      acc[2 * (q)][ni] = __builtin_amdgcn_mfma_f32_16x16x32_bf16(a00, bfr[ni][0], acc[2 * (q)][ni], 0, 0, 0); \
    _Pragma("unroll") \
    for (int ni = 0; ni < 4; ++ni) \
      acc[2 * (q) + 1][ni] = __builtin_amdgcn_mfma_f32_16x16x32_bf16(a10, bfr[ni][0], acc[2 * (q) + 1][ni], 0, 0, 0); \
    _Pragma("unroll") \
    for (int ni = 0; ni < 4; ++ni) \
      acc[2 * (q)][ni] = __builtin_amdgcn_mfma_f32_16x16x32_bf16(a01, bfr[ni][1], acc[2 * (q)][ni], 0, 0, 0); \
    _Pragma("unroll") \
    for (int ni = 0; ni < 4; ++ni) \
      acc[2 * (q) + 1][ni] = __builtin_amdgcn_mfma_f32_16x16x32_bf16(a11, bfr[ni][1], acc[2 * (q) + 1][ni], 0, 0, 0); \
    __builtin_amdgcn_s_setprio(0); \
    TAIL_STMT; \
    __builtin_amdgcn_s_barrier(); \
  } while (0)

  for (int j = 0; j < JI; ++j) {
    const int t1 = 2 * j + 1, t2 = 2 * j + 2, t3 = 2 * j + 3;
    const bool g2 = (t2 < T), g3 = (t3 < T);
    // phases 1-4: consume tile 2j (buf0)
    PHASE(0, 0, 1, { STAGE_A(0, t1, 1); }, {});
    PHASE(0, 1, 0, { STAGE_A(1, t1, 1); }, {});
    PHASE(0, 2, 0, { if (g2) STAGE_B(0, t2, 0); }, {});
    PHASE(0, 3, 0, { if (g2) STAGE_B(1, t2, 0); },
          { if (g2) { asm volatile("s_waitcnt vmcnt(4)" ::: "memory"); }
            else    { asm volatile("s_waitcnt vmcnt(0)" ::: "memory"); } });
    // phases 5-8: consume tile 2j+1 (buf1)
    PHASE(1, 0, 1, { if (g2) STAGE_A(0, t2, 0); }, {});
    PHASE(1, 1, 0, { if (g2) STAGE_A(1, t2, 0); }, {});
    PHASE(1, 2, 0, { if (g3) STAGE_B(0, t3, 1); }, {});
    PHASE(1, 3, 0, { if (g3) STAGE_B(1, t3, 1); },
          { if (j + 1 < JI) {
              if (g3) { asm volatile("s_waitcnt vmcnt(4)" ::: "memory"); }
              else    { asm volatile("s_waitcnt vmcnt(0)" ::: "memory"); } } });
  }

#undef PHASE
#undef READ_BFR
#undef STAGE_A
#undef STAGE_B

  // ---------- GLU epilogue: stage bf16 [256][136] in LDS, coalesced write ----------
  // All async16 retired (last-iter ph4 drains vmcnt(0)); all LDS reads done (ph8 barrier).
  #pragma unroll
  for (int ni = 0; ni < 4; ++ni) {
    int lc = wn + ni * 16 + l16;
    int gi = (bn + lc) >> 1;
    float bv = bias[(l16 & 1) ? 4096 + gi : gi];
    #pragma unroll
    for (int mi = 0; mi < 8; ++mi) {
      #pragma unroll
      for (int r = 0; r < 4; ++r) {
        float v = acc[mi][ni][r] + bv;
        float p = __shfl_xor(v, 1);
        if ((l16 & 1) == 0) {
          int lr = wm + mi * 16 + quad * 4 + r;
          float g = (v / (1.f + __expf(-v))) * p;
          smem[lr * 136 + (lc >> 1)] = f2b(g);
        }
      }
    }
  }
  __syncthreads();
  {
    int lr = tid >> 1, half = (tid & 1) * 64;
    unsigned short* dst = out + (size_t)(bm + lr) * (N >> 1) + (bn >> 1) + half;
    const unsigned short* src = smem + lr * 136 + half;
    #pragma unroll
    for (int j = 0; j < 8; ++j)
      ((uint4*)dst)[j] = *(const uint4*)(src + j * 8);
  }
}

// ---------------- flash attention (S^T, Q-tile 128, K-tile 64, 8 waves) ----------------
// Round-6 dbuf (1 barrier/K-tile) + round-7 T13/T5/T17 kept (all null but free).

__global__ __launch_bounds__(512, 1) void attn_kernel(
    const unsigned short* __restrict__ q, const unsigned short* __restrict__ k,
    const unsigned short* __restrict__ vt, const int* __restrict__ amask,
    unsigned short* __restrict__ o) {
  const int bh = blockIdx.x;
  const int b = bh >> 4, h = bh & 15;
  const int qt = blockIdx.y;
  const int tid = threadIdx.x;
  const int wave = tid >> 6, lane = tid & 63;
  const int quad = lane >> 4, l16 = lane & 15;
  const int h7 = l16 & 7;
  const int kc0 = (quad ^ h7) * 8;
  const int kc1 = ((quad + 4) ^ h7) * 8;

  const unsigned short* qb = q  + (size_t)bh * 2048 * 64;
  const unsigned short* kb = k  + (size_t)bh * 2048 * 64;
  const unsigned short* vb = vt + (size_t)bh * 64 * 2048;

  __shared__ __align__(16) unsigned short Ks[2][64 * 64];   // 2x 8 KB, chunk-swizzled
  __shared__ __align__(16) unsigned short Vs[2][64 * 64];   // 2x 8 KB, chunk-swizzled
  __shared__ __align__(16) unsigned short Ps[8 * 16 * 72];  // per-wave P / epilogue stage (18 KB)
  __shared__ float biasf[2][64];

  unsigned short* PsW = Ps + wave * 1152;

  const int qrow = qt * 128 + wave * 16 + l16;
  bf16x8 qa0 = *reinterpret_cast<const bf16x8*>(&qb[(size_t)qrow * 64 + quad * 8]);
  bf16x8 qa1 = *reinterpret_cast<const bf16x8*>(&qb[(size_t)qrow * 64 + 32 + quad * 8]);

  f32x4 oacc[4] = {};
  float mrow = -30000.f, lrow = 0.f;

  // prefetch tile 0: 512 threads x 16B = one 8KB tile each for K and V
  uint4 kpre, vpre;
  {
    int key = tid >> 3, dl = (tid & 7) ^ (key & 7);
    kpre = *(const uint4*)(kb + key * 64 + dl * 8);
    int d = tid >> 3, kl = (tid & 7) ^ (d & 7);
    vpre = *(const uint4*)(vb + (size_t)d * 2048 + kl * 8);
  }
  int mv = (tid < 64) ? amask[b * 2048 + tid] : 0;

  for (int kt = 0; kt < 32; ++kt) {
    const int cb = kt & 1;
    // store tile kt (in regs) into buf[cb]; overlaps previous tile's compute tail
    ((uint4*)Ks[cb])[tid] = kpre;
    ((uint4*)Vs[cb])[tid] = vpre;
    if (tid < 64) biasf[cb][tid] = mv ? 0.f : -30000.f;
    __syncthreads();   // the ONE barrier: publishes tile-kt stores; prior reads of buf[cb] done

    if (kt + 1 < 32) {   // prefetch next tile during compute
      int key = tid >> 3, dl = (tid & 7) ^ (key & 7);
      kpre = *(const uint4*)(kb + (size_t)(kt + 1) * 4096 + key * 64 + dl * 8);
      int d = tid >> 3, kl = (tid & 7) ^ (d & 7);
      vpre = *(const uint4*)(vb + (size_t)d * 2048 + (kt + 1) * 64 + kl * 8);
      mv = (tid < 64) ? amask[b * 2048 + (kt + 1) * 64 + tid] : 0;
    }

    // S^T: lane holds S[q=l16][key=nt*16+quad*4+r]
    f32x4 st[4];
    __builtin_amdgcn_s_setprio(1);
    #pragma unroll
    for (int nt = 0; nt < 4; ++nt) {
      bf16x8 ka0 = *reinterpret_cast<const bf16x8*>(&Ks[cb][(nt * 16 + l16) * 64 + kc0]);
      bf16x8 ka1 = *reinterpret_cast<const bf16x8*>(&Ks[cb][(nt * 16 + l16) * 64 + kc1]);
      f32x4 bv = *reinterpret_cast<const f32x4*>(&biasf[cb][nt * 16 + quad * 4]);
      f32x4 z = {};
      z = __builtin_amdgcn_mfma_f32_16x16x32_bf16(ka0, qa0, z, 0, 0, 0);
      z = __builtin_amdgcn_mfma_f32_16x16x32_bf16(ka1, qa1, z, 0, 0, 0);
      st[nt] = z + bv;
    }
    __builtin_amdgcn_s_setprio(0);

    // row max via pairwise tree (seeds v_max3/v_max fusion)
    float m01 = fmaxf(fmaxf(st[0][0], st[0][1]), fmaxf(st[0][2], st[0][3]));
    float m23 = fmaxf(fmaxf(st[1][0], st[1][1]), fmaxf(st[1][2], st[1][3]));
    float m45 = fmaxf(fmaxf(st[2][0], st[2][1]), fmaxf(st[2][2], st[2][3]));
    float m67 = fmaxf(fmaxf(st[3][0], st[3][1]), fmaxf(st[3][2], st[3][3]));
    float tm = fmaxf(fmaxf(m01, m23), fmaxf(m45, m67));
    tm = fmaxf(tm, __shfl_xor(tm, 16));
    tm = fmaxf(tm, __shfl_xor(tm, 32));

    // T13 defer-max: skip rescale when no row in the wave grew past mrow+8
    const bool defer = __all(tm <= mrow + 8.f);
    if (!defer) {
      float mnew = fmaxf(mrow, tm);
      float alpha = __expf(mrow - mnew);
      mrow = mnew;
      float a0 = __shfl(alpha, quad * 4 + 0);
      float a1 = __shfl(alpha, quad * 4 + 1);
      float a2 = __shfl(alpha, quad * 4 + 2);
      float a3 = __shfl(alpha, quad * 4 + 3);
      #pragma unroll
      for (int dt = 0; dt < 4; ++dt) {
        oacc[dt][0] *= a0; oacc[dt][1] *= a1; oacc[dt][2] *= a2; oacc[dt][3] *= a3;
      }
      lrow *= alpha;
    }

    float rs = 0.f;
    #pragma unroll
    for (int nt = 0; nt < 4; ++nt) {
      float p0 = __expf(st[nt][0] - mrow);
      float p1 = __expf(st[nt][1] - mrow);
      float p2 = __expf(st[nt][2] - mrow);
      float p3 = __expf(st[nt][3] - mrow);
      rs += (p0 + p1) + (p2 + p3);
      uint2 w;
      w.x = packtrunc(p0, p1);
      w.y = packtrunc(p2, p3);
      *(uint2*)&PsW[l16 * 72 + nt * 16 + quad * 4] = w;
    }
    rs += __shfl_xor(rs, 16);
    rs += __shfl_xor(rs, 32);
    lrow += rs;

    // PV: A = P rows (per-wave LDS), B = V^T rows
    bf16x8 pa0 = *reinterpret_cast<const bf16x8*>(&PsW[l16 * 72 + quad * 8]);
    bf16x8 pa1 = *reinterpret_cast<const bf16x8*>(&PsW[l16 * 72 + 32 + quad * 8]);
    __builtin_amdgcn_s_setprio(1);
    #pragma unroll
    for (int dt = 0; dt < 4; ++dt) {
      bf16x8 vb0 = *reinterpret_cast<const bf16x8*>(&Vs[cb][(dt * 16 + l16) * 64 + kc0]);
      bf16x8 vb1 = *reinterpret_cast<const bf16x8*>(&Vs[cb][(dt * 16 + l16) * 64 + kc1]);
      oacc[dt] = __builtin_amdgcn_mfma_f32_16x16x32_bf16(pa0, vb0, oacc[dt], 0, 0, 0);
      oacc[dt] = __builtin_amdgcn_mfma_f32_16x16x32_bf16(pa1, vb1, oacc[dt], 0, 0, 0);
    }
    __builtin_amdgcn_s_setprio(0);
  }

  // epilogue: normalize, stage all 128 rows in Ps, coalesced writes
  float invl = lrow > 0.f ? 1.f / lrow : 0.f;
  float i0 = __shfl(invl, quad * 4 + 0);
  float i1 = __shfl(invl, quad * 4 + 1);
  float i2 = __shfl(invl, quad * 4 + 2);
  float i3 = __shfl(invl, quad * 4 + 3);
  __syncthreads();
  #pragma unroll
  for (int dt = 0; dt < 4; ++dt) {
    int lr = wave * 16 + quad * 4;
    Ps[(lr + 0) * 72 + dt * 16 + l16] = f2b(oacc[dt][0] * i0);
    Ps[(lr + 1) * 72 + dt * 16 + l16] = f2b(oacc[dt][1] * i1);
    Ps[(lr + 2) * 72 + dt * 16 + l16] = f2b(oacc[dt][2] * i2);
    Ps[(lr + 3) * 72 + dt * 16 + l16] = f2b(oacc[dt][3] * i3);
  }
  __syncthreads();
  {
    int lr = tid >> 2, cb2 = (tid & 3) * 16;
    int n = qt * 128 + lr;
    unsigned short* dst = o + ((size_t)(b * 2048 + n)) * 1024 + h * 64 + cb2;
    const unsigned short* src = Ps + lr * 72 + cb2;
    ((uint4*)dst)[0] = *(const uint4*)(src);
    ((uint4*)dst)[1] = *(const uint4*)(src + 8);
  }
}

// ---------------- launch ----------------

extern "C" void kernel_launch(void* const* d_in, const int* in_sizes, int n_in,
                              void* d_out, int out_size, void* d_ws, size_t ws_size,
                              hipStream_t stream) {
  const float* x       = (const float*)d_in[0];
  const float* c       = (const float*)d_in[1];
  const int*   amask   = (const int*)d_in[2];
  const float* norm_w  = (const float*)d_in[3];
  const float* scale_w = (const float*)d_in[4];
  const float* scale_b = (const float*)d_in[5];
  const float* shift_w = (const float*)d_in[6];
  const float* shift_b = (const float*)d_in[7];
  const float* qkv_w   = (const float*)d_in[8];
  const float* proj_w  = (const float*)d_in[9];
  const float* proj_b  = (const float*)d_in[10];
  const float* mlp_w1  = (const float*)d_in[11];
  const float* mlp_b1  = (const float*)d_in[12];
  const float* mlp_w2  = (const float*)d_in[13];
  const float* mlp_b2  = (const float*)d_in[14];

  char* ws = (char*)d_ws;
  unsigned short* wqkv  = (unsigned short*)(ws + 0);
  unsigned short* wproj = (unsigned short*)(ws + 6291456);
  unsigned short* wmlp1 = (unsigned short*)(ws + 8388608);   // interleaved gate/up rows
  unsigned short* wmlp2 = (unsigned short*)(ws + 25165824);
  float* scale_o        = (float*)(ws + 33554432);
  float* shift_o        = (float*)(ws + 33562624);
  unsigned short* hbuf  = (unsigned short*)(ws + 33570816);
  unsigned short* qbuf  = (unsigned short*)(ws + 41959424);
  unsigned short* kbuf  = (unsigned short*)(ws + 50348032);
  unsigned short* vbuf  = (unsigned short*)(ws + 58736640);
  unsigned short* abuf  = (unsigned short*)(ws + 67125248);
  unsigned short* gbuf  = qbuf;
  float* x1             = (float*)(ws + 75513856);

  cvt4_kernel<<<16384, 256, 0, stream>>>(qkv_w, proj_w, mlp_w1, mlp_w2,
                                         wqkv, wproj, wmlp1, wmlp2);

  cond_kernel<<<32, 256, 0, stream>>>(c, scale_w, scale_b, shift_w, shift_b, scale_o, shift_o);

  adaln_kernel<<<4096, 256, 0, stream>>>(x, norm_w, scale_o, shift_o, hbuf);

  gemm_k<1, 128><<<dim3(24, 32), 256, 0, stream>>>(hbuf, wqkv, nullptr, nullptr,
                                                   qbuf, kbuf, vbuf, 4096, 3072, 1024);

  attn_kernel<<<dim3(32, 16), 512, 0, stream>>>(qbuf, kbuf, vbuf, amask, abuf);

  gemm_k<0, 64><<<dim3(8, 64), 256, 0, stream>>>(abuf, wproj, proj_b, x,
                                                 x1, nullptr, nullptr, 4096, 1024, 1024);

  adaln_kernel<<<4096, 256, 0, stream>>>(x1, norm_w, scale_o, shift_o, hbuf);

  gemm256_glu<<<dim3(32, 16), 512, 0, stream>>>(hbuf, wmlp1, mlp_b1, gbuf, 4096, 8192, 1024);

  gemm_k<0, 64><<<dim3(8, 64), 256, 0, stream>>>(gbuf, wmlp2, mlp_b2, x1,
                                                 d_out, nullptr, nullptr, 4096, 1024, 4096);

  (void)in_sizes; (void)n_in; (void)out_size; (void)ws_size;
}

// Round 10
// 436.420 us; speedup vs baseline: 1.0516x; 1.0516x over previous
//
#include <hip/hip_runtime.h>
#include <cstdint>
#include <cstddef>

#define DEVINL __device__ __forceinline__

typedef __bf16 bf16x8 __attribute__((ext_vector_type(8)));
typedef float  f32x4  __attribute__((ext_vector_type(4)));

// ---------------- helpers ----------------

DEVINL unsigned short f2b(float f) {   // f32 -> bf16 bits, round-to-nearest-even
  unsigned u = __builtin_bit_cast(unsigned, f);
  u += 0x7fffu + ((u >> 16) & 1u);
  return (unsigned short)(u >> 16);
}

DEVINL unsigned packtrunc(float a, float b) {  // 2x f32 -> packed bf16 (truncate)
  unsigned ua = __builtin_bit_cast(unsigned, a);
  unsigned ub = __builtin_bit_cast(unsigned, b);
  return (ua >> 16) | (ub & 0xffff0000u);
}

DEVINL void async16(void* lds, const void* g) {
  __builtin_amdgcn_global_load_lds((const __attribute__((address_space(1))) unsigned*)g,
                                   (__attribute__((address_space(3))) unsigned*)lds,
                                   16, 0, 0);
}

// ---------------- fused prep: weight f32->bf16 cast (4 weights) + conditioning ----------------
// ROUND-10: cond merged into cvt4 (blocks 16384..16415) - one fewer launch; cond's 32
// blocks overlap the cvt4 tail instead of serializing behind it. Block-uniform branch.
// mlp_w1 rows INTERLEAVED: gate row i -> 2i, up row i -> 2i+1 (GLU via shfl_xor(1)).

__global__ void prep_kernel(const float* __restrict__ s0, const float* __restrict__ s1,
                            const float* __restrict__ s2, const float* __restrict__ s3,
                            unsigned short* __restrict__ d0, unsigned short* __restrict__ d1,
                            unsigned short* __restrict__ d2, unsigned short* __restrict__ d3,
                            const float* __restrict__ c,
                            const float* __restrict__ scale_w, const float* __restrict__ scale_b,
                            const float* __restrict__ shift_w, const float* __restrict__ shift_b,
                            float* __restrict__ scale_o, float* __restrict__ shift_o) {
  __shared__ float sc[1024];
  __shared__ float red[2][4][64];
  const int bid = blockIdx.x;
  const int tid = threadIdx.x;

  if (bid < 16384) {
    // -------- cvt4 path --------
    int i = bid * 256 + tid;   // float4 index, total 4194304
    if (i < 786432) {
      float4 v = ((const float4*)s0)[i];
      ushort4 o; o.x = f2b(v.x); o.y = f2b(v.y); o.z = f2b(v.z); o.w = f2b(v.w);
      ((ushort4*)d0)[i] = o;
    } else if (i < 1048576) {
      int off = i - 786432;
      float4 v = ((const float4*)s1)[off];
      ushort4 o; o.x = f2b(v.x); o.y = f2b(v.y); o.z = f2b(v.z); o.w = f2b(v.w);
      ((ushort4*)d1)[off] = o;
    } else if (i < 3145728) {
      int off = i - 1048576;                  // mlp_w1: 8192 rows x 256 float4
      int row = off >> 8, col = off & 255;
      int rp = (row < 4096) ? (row << 1) : (((row - 4096) << 1) | 1);
      float4 v = ((const float4*)s2)[off];
      ushort4 o; o.x = f2b(v.x); o.y = f2b(v.y); o.z = f2b(v.z); o.w = f2b(v.w);
      ((ushort4*)d2)[rp * 256 + col] = o;
    } else {
      int off = i - 3145728;
      float4 v = ((const float4*)s3)[off];
      ushort4 o; o.x = f2b(v.x); o.y = f2b(v.y); o.z = f2b(v.z); o.w = f2b(v.w);
      ((ushort4*)d3)[off] = o;
    }
  } else {
    // -------- cond path: silu(c) @ {shift,scale}_w^T + b --------
    const int cb = bid - 16384;                 // [0,32)
    const int b = cb >> 4, ch = cb & 15;
    for (int i = tid; i < 1024; i += 256) {
      float cv = c[b * 1024 + i];
      sc[i] = cv / (1.f + __expf(-cv));
    }
    __syncthreads();
    int colidx = tid & 63, p = tid >> 6;
    int co = ch * 64 + colidx;
    float dsc = 0.f, dsh = 0.f;
    for (int i = 0; i < 256; ++i) {
      int kk = p * 256 + i;
      float s = sc[kk];
      dsc += s * scale_w[(size_t)co * 1024 + kk];
      dsh += s * shift_w[(size_t)co * 1024 + kk];
    }
    red[0][p][colidx] = dsc;
    red[1][p][colidx] = dsh;
    __syncthreads();
    if (p == 0) {
      float s4  = red[0][0][colidx] + red[0][1][colidx] + red[0][2][colidx] + red[0][3][colidx];
      float sh4 = red[1][0][colidx] + red[1][1][colidx] + red[1][2][colidx] + red[1][3][colidx];
      scale_o[b * 1024 + co] = fminf(fmaxf(s4 + scale_b[co] + 1.f, 0.1f), 10.f);
      shift_o[b * 1024 + co] = sh4 + shift_b[co];
    }
  }
}

// ---------------- adaLN ----------------

__global__ __launch_bounds__(256) void adaln_kernel(const float* __restrict__ x,
                                                    const float* __restrict__ norm_w,
                                                    const float* __restrict__ scale,
                                                    const float* __restrict__ shift,
                                                    unsigned short* __restrict__ h) {
  int row = blockIdx.x;
  int b = row >> 11;
  int tid = threadIdx.x;
  float4 v = ((const float4*)(x + (size_t)row * 1024))[tid];
  float ss = v.x * v.x + v.y * v.y + v.z * v.z + v.w * v.w;
  #pragma unroll
  for (int d = 32; d; d >>= 1) ss += __shfl_xor(ss, d);
  __shared__ float wsum[4];
  if ((tid & 63) == 0) wsum[tid >> 6] = ss;
  __syncthreads();
  float tot = wsum[0] + wsum[1] + wsum[2] + wsum[3];
  float inv = 1.f / fmaxf(sqrtf(tot * (1.f / 1024.f)), 1e-6f);
  float4 nw  = ((const float4*)norm_w)[tid];
  float4 scv = ((const float4*)(scale + b * 1024))[tid];
  float4 shv = ((const float4*)(shift + b * 1024))[tid];
  ushort4 o;
  o.x = f2b(v.x * inv * nw.x * scv.x + shv.x);
  o.y = f2b(v.y * inv * nw.y * scv.y + shv.y);
  o.z = f2b(v.z * inv * nw.z * scv.z + shv.z);
  o.w = f2b(v.w * inv * nw.w * scv.w + shv.w);
  ((ushort4*)(h + (size_t)row * 1024))[tid] = o;
}

// ---------------- MT x 128 bf16 MFMA GEMM with 2-slot async ring (BK=64):  C = A @ B^T ----
// ROUND-10: reverted to the round-8 BK=64 ring (best-measured: 456.9 us). BK=32 (round 9)
// was null-to-negative: extra barrier-pair per step ~ cancels the occupancy gain.
// Ring: step t+2 issued AFTER compute(t); top-of-iter vmcnt(L) (L=6 for MT=64, 8 for
// MT=128) retires step t with one full compute phase of flight; vmcnt(0) final step only.
// LDS: MT=64 EPI0 48 KB (3 blk/CU); MT=128 EPI1 64 KB (2 blk/CU). Math/epilogues identical.

template<int EPI, int MT>
__global__ __launch_bounds__(256, 1) void gemm_k(
    const unsigned short* __restrict__ A,
    const unsigned short* __restrict__ B0,
    const float* __restrict__ bias0,
    const float* __restrict__ resid,
    void* __restrict__ out0_, void* __restrict__ out1_, void* __restrict__ out2_,
    int M, int N, int K) {
  constexpr int MI = MT / 32;              // m-frags per wave
  constexpr int A_SH = MT * 32;            // shorts per A half-buffer (BK=32 half)
  constexpr int SLOT_SH = 2 * A_SH + 2 * 4096;   // one ring slot (A halves + B halves)
  constexpr int RING_SH = 2 * SLOT_SH;
  constexpr int STAGE_SH = (EPI == 1) ? 128 * 136 : (EPI == 2 ? 128 * 72 : 0);
  constexpr int SMEM_SH = (RING_SH > STAGE_SH) ? RING_SH : STAGE_SH;
  __shared__ __align__(16) unsigned short smem[SMEM_SH];

  const int tid = threadIdx.x;
  const int wave = tid >> 6, lane = tid & 63;
  const int quad = lane >> 4, l16 = lane & 15;
  const int wm = (wave >> 1) * (MT / 2), wn = (wave & 1) * 64;
  const int bm = blockIdx.y * MT, bn = blockIdx.x * 128;

  f32x4 acc[MI][4] = {};
  const int steps = K >> 6;

  // stage K-step s into ring slot r (L = MT/64*2 + 4 async16 per thread)
  auto STAGE = [&](int s, int r) {
    const int k0 = s << 6;
    unsigned short* base = smem + r * SLOT_SH;
    #pragma unroll
    for (int i = 0; i < MT / 64; ++i) {
      int cc = i * 256 + tid;
      int rr = cc >> 2, ko = (cc & 3) << 3;
      size_t ga = (size_t)(bm + rr) * K + k0 + ko;
      async16(base + (i * 2048 + wave * 512), A + ga);          // As0
      async16(base + A_SH + (i * 2048 + wave * 512), A + ga + 32);  // As1
    }
    #pragma unroll
    for (int i = 0; i < 2; ++i) {
      int cc = i * 256 + tid;
      int rr = cc >> 2, ko = (cc & 3) << 3;
      size_t gb = (size_t)(bn + rr) * K + k0 + ko;
      async16(base + 2 * A_SH + (i * 2048 + wave * 512), B0 + gb);          // Bs0
      async16(base + 2 * A_SH + 4096 + (i * 2048 + wave * 512), B0 + gb + 32);  // Bs1
    }
  };

  // prologue: stage steps 0 and 1
  STAGE(0, 0);
  if (steps > 1) STAGE(1, 1);

  for (int s = 0; s < steps; ++s) {
    // retire step s: exactly step s+1's L loads may remain in flight
    if (s < steps - 1) {
      if constexpr (MT == 64) asm volatile("s_waitcnt vmcnt(6)" ::: "memory");
      else                    asm volatile("s_waitcnt vmcnt(8)" ::: "memory");
    } else {
      asm volatile("s_waitcnt vmcnt(0)" ::: "memory");
    }
    __builtin_amdgcn_s_barrier();

    const unsigned short* base = smem + (s & 1) * SLOT_SH;
    #pragma unroll
    for (int ks = 0; ks < 2; ++ks) {
      const unsigned short* Ah = base + (ks ? A_SH : 0);
      const unsigned short* Bh = base + 2 * A_SH + (ks ? 4096 : 0);
      bf16x8 af[MI], bfr[4];
      #pragma unroll
      for (int mi = 0; mi < MI; ++mi)
        af[mi] = *reinterpret_cast<const bf16x8*>(&Ah[(wm + mi * 16 + l16) * 32 + quad * 8]);
      #pragma unroll
      for (int ni = 0; ni < 4; ++ni)
        bfr[ni] = *reinterpret_cast<const bf16x8*>(&Bh[(wn + ni * 16 + l16) * 32 + quad * 8]);
      #pragma unroll
      for (int mi = 0; mi < MI; ++mi)
        #pragma unroll
        for (int ni = 0; ni < 4; ++ni)
          acc[mi][ni] = __builtin_amdgcn_mfma_f32_16x16x32_bf16(af[mi], bfr[ni], acc[mi][ni], 0, 0, 0);
    }

    // all waves done reading slot s&1, then refill it with step s+2
    asm volatile("s_waitcnt lgkmcnt(0)" ::: "memory");
    __builtin_amdgcn_s_barrier();
    if (s + 2 < steps) STAGE(s + 2, s & 1);
  }
  // final iter drained vmcnt(0) at top and issued nothing after -> smem reusable.

  // ---------- epilogue: C/D layout col=lane&15, row=quad*4+reg ----------
  if constexpr (EPI == 0) {
    #pragma unroll
    for (int mi = 0; mi < MI; ++mi) {
      #pragma unroll
      for (int ni = 0; ni < 4; ++ni) {
        int gc = bn + wn + ni * 16 + l16;
        #pragma unroll
        for (int r = 0; r < 4; ++r) {
          int gr = bm + wm + mi * 16 + quad * 4 + r;
          ((float*)out0_)[(size_t)gr * N + gc] = acc[mi][ni][r] + bias0[gc] + resid[(size_t)gr * N + gc];
        }
      }
    }
  } else if constexpr (EPI == 1) {
    const int region = bn >> 10;          // 0=q, 1=k, 2=v
    __syncthreads();
    #pragma unroll
    for (int mi = 0; mi < MI; ++mi) {
      #pragma unroll
      for (int ni = 0; ni < 4; ++ni) {
        int lc = wn + ni * 16 + l16;
        #pragma unroll
        for (int r = 0; r < 4; ++r) {
          int lr = wm + mi * 16 + quad * 4 + r;
          float v = acc[mi][ni][r];
          if (region == 0)      smem[lr * 136 + lc] = f2b(v * 0.125f);
          else if (region == 1) smem[lr * 136 + lc] = f2b(v);
          else                  smem[lc * 136 + lr] = f2b(v);   // transpose for v
        }
      }
    }
    __syncthreads();
    const int b = bm >> 11;
    const int bnm = bn & 1023;
    if (region <= 1) {
      int lr = tid >> 1, hl = tid & 1;
      int n = (bm + lr) & 2047;
      int hh = (bnm >> 6) + hl;
      unsigned short* dst = (unsigned short*)(region == 0 ? out0_ : out1_) +
                            (((size_t)(b * 16 + hh)) * 2048 + n) * 64;
      const unsigned short* src = smem + lr * 136 + hl * 64;
      #pragma unroll
      for (int j = 0; j < 8; ++j)
        ((uint4*)dst)[j] = *(const uint4*)(src + j * 8);
    } else {
      int lc = tid >> 1, nh = tid & 1;
      int c2 = bnm + lc;
      int hh = c2 >> 6, d = c2 & 63;
      int nbase = (bm & 2047) + nh * 64;
      unsigned short* dst = (unsigned short*)out2_ +
                            (((size_t)(b * 16 + hh)) * 64 + d) * 2048 + nbase;
      const unsigned short* src = smem + lc * 136 + nh * 64;
      #pragma unroll
      for (int j = 0; j < 8; ++j)
        ((uint4*)dst)[j] = *(const uint4*)(src + j * 8);
    }
  } else {   // EPI 2: interleaved GLU -> bf16 [M, N/2]
    __syncthreads();
    #pragma unroll
    for (int mi = 0; mi < MI; ++mi) {
      #pragma unroll
      for (int ni = 0; ni < 4; ++ni) {
        int lc = wn + ni * 16 + l16;
        int gcp = bn + lc;
        int gi = gcp >> 1;
        float bias = bias0[(gcp & 1) ? 4096 + gi : gi];
        #pragma unroll
        for (int r = 0; r < 4; ++r) {
          int lr = wm + mi * 16 + quad * 4 + r;
          float v = acc[mi][ni][r] + bias;
          float p = __shfl_xor(v, 1);
          if ((l16 & 1) == 0) {
            float g = (v / (1.f + __expf(-v))) * p;
            smem[lr * 72 + (lc >> 1)] = f2b(g);
          }
        }
      }
    }
    __syncthreads();
    int lr = tid >> 1, ch = (tid & 1) * 32;
    unsigned short* dst = (unsigned short*)out0_ + (size_t)(bm + lr) * (N >> 1) + (bn >> 1) + ch;
    const unsigned short* src = smem + lr * 72 + ch;
    #pragma unroll
    for (int j = 0; j < 4; ++j)
      ((uint4*)dst)[j] = *(const uint4*)(src + j * 8);
  }
}

// ---------------- 256x256 bf16 MFMA GEMM, 8-phase schedule + XCD column-ownership ----------------
// C = A[M,K] @ B[N,K]^T, fused interleaved-GLU epilogue -> bf16 [M, N/2].
// XCD x owns bx in {4x..4x+3} (2 MiB B, L2-resident); FETCH_SIZE verified 135->49 MB.
// Pinned at ~667 TF across 3 schedules x 2 mappings (lockstep at 1 blk/CU). Structural.

__global__ __launch_bounds__(512, 2) void gemm256_glu(
    const unsigned short* __restrict__ A,
    const unsigned short* __restrict__ B,
    const float* __restrict__ bias,
    unsigned short* __restrict__ out,
    int M, int N, int K) {
  // shorts: [0,16384) A buf0 | [16384,32768) A buf1 | [32768,49152) B buf0 | [49152,65536) B buf1
  __shared__ __align__(16) unsigned short smem[65536];   // 128 KiB

  const int tid  = threadIdx.x;
  const int wave = tid >> 6, lane = tid & 63;
  const int quad = lane >> 4, l16 = lane & 15;
  const int wm = (wave >> 2) * 128, wn = (wave & 3) * 64;

  // XCD column-ownership mapping. Grid is exactly (32,16).
  const int lin = blockIdx.y * gridDim.x + blockIdx.x;
  const int xcd = lin & 7, idx = lin >> 3;     // idx in [0,64)
  const int bx = (xcd << 2) + (idx & 3);       // [0,32): 4 N-panels per XCD
  const int by = idx >> 2;                     // [0,16)
  const int bm = by * 256, bn = bx * 256;

  // staging: thread covers 2 chunks per half-tile (rows tid>>3 and +64),
  // same swizzled k-chunk for both (row&7 identical). Linear LDS dest.
  const int srow = tid >> 3;
  const int slc  = (tid & 7) ^ (srow & 7);
  const unsigned short* gA0 = A + (size_t)(bm + srow) * K + slc * 8;
  const unsigned short* gB0 = B + (size_t)(bn + srow) * K + slc * 8;
  const size_t rstep = (size_t)64 * K;

#define STAGE_A(h, tk, d) do { \
    const unsigned short* s_ = gA0 + (size_t)(h) * 128 * K + (size_t)(tk) * 64; \
    async16(smem + (d) * 16384 + (h) * 8192 + tid * 8, s_); \
    async16(smem + (d) * 16384 + (h) * 8192 + 4096 + tid * 8, s_ + rstep); \
  } while (0)
#define STAGE_B(h, tk, d) do { \
    const unsigned short* s_ = gB0 + (size_t)(h) * 128 * K + (size_t)(tk) * 64; \
    async16(smem + 32768 + (d) * 16384 + (h) * 8192 + tid * 8, s_); \
    async16(smem + 32768 + (d) * 16384 + (h) * 8192 + 4096 + tid * 8, s_ + rstep); \
  } while (0)

  const int pc0 = (quad ^ (l16 & 7)) * 8;         // swizzled chunk offset, k-half 0
  const int pc1 = ((quad + 4) ^ (l16 & 7)) * 8;   // k-half 1
  const int arow = wm + l16;
  const int brow = wn + l16;

  f32x4 acc[8][4] = {};
  bf16x8 bfr[4][2];
  const int T = K >> 6;        // 16 K-tiles
  const int JI = T >> 1;       // 8 iterations, 2 tiles each

  // ---- prologue: t0.B, t0.A -> buf0; t1.B -> buf1 (t1.B issued LAST) ----
  STAGE_B(0, 0, 0); STAGE_B(1, 0, 0);
  STAGE_A(0, 0, 0); STAGE_A(1, 0, 0);
  STAGE_B(0, 1, 1); STAGE_B(1, 1, 1);
  asm volatile("s_waitcnt vmcnt(4)" ::: "memory");   // tile-0 (8 oldest) landed
  __builtin_amdgcn_s_barrier();

#define READ_BFR(d) do { \
    _Pragma("unroll") \
    for (int ni = 0; ni < 4; ++ni) { \
      int rb = 32768 + (d) * 16384 + (brow + ni * 16) * 64; \
      bfr[ni][0] = *reinterpret_cast<const bf16x8*>(&smem[rb + pc0]); \
      bfr[ni][1] = *reinterpret_cast<const bf16x8*>(&smem[rb + pc1]); \
    } \
  } while (0)

#define PHASE(d, q, RB, STAGE_STMT, TAIL_STMT) do { \
    bf16x8 a00, a01, a10, a11; \
    if (RB) READ_BFR(d); \
    { int ra = (d) * 16384 + (arow + (2 * (q)) * 16) * 64; \
      a00 = *reinterpret_cast<const bf16x8*>(&smem[ra + pc0]); \
      a01 = *reinterpret_cast<const bf16x8*>(&smem[ra + pc1]); \
      a10 = *reinterpret_cast<const bf16x8*>(&smem[ra + 1024 + pc0]); \
      a11 = *reinterpret_cast<const bf16x8*>(&smem[ra + 1024 + pc1]); } \
    STAGE_STMT; \
    if (RB) asm volatile("s_waitcnt lgkmcnt(8)" ::: "memory"); \
    __builtin_amdgcn_s_barrier(); \
    asm volatile("s_waitcnt lgkmcnt(0)" ::: "memory"); \
    __builtin_amdgcn_sched_barrier(0); \
    __builtin_amdgcn_s_setprio(1); \
    _Pragma("unroll") \
    for (int ni = 0; ni < 4; ++ni) \
      acc[2 * (q)][ni] = __builtin_amdgcn_mfma_f32_16x16x32_bf16(a00, bfr[ni][0], acc[2 * (q)][ni], 0, 0, 0); \
    _Pragma("unroll") \
    for (int ni = 0; ni < 4; ++ni) \
      acc[2 * (q) + 1][ni] = __builtin_amdgcn_mfma_f32_16x16x32_bf16(a10, bfr[ni][0], acc[2 * (q) + 1][ni], 0, 0, 0); \
    _Pragma("unroll") \
    for (int ni = 0; ni < 4; ++ni) \
      acc[2 * (q)][ni] = __builtin_amdgcn_mfma_f32_16x16x32_bf16(a01, bfr[ni][1], acc[2 * (q)][ni], 0, 0, 0); \
    _Pragma("unroll") \
    for (int ni = 0; ni < 4; ++ni) \
      acc[2 * (q) + 1][ni] = __builtin_amdgcn_mfma_f32_16x16x32_bf16(a11, bfr[ni][1], acc[2 * (q) + 1][ni], 0, 0, 0); \
    __builtin_amdgcn_s_setprio(0); \
    TAIL_STMT; \
    __builtin_amdgcn_s_barrier(); \
  } while (0)

  for (int j = 0; j < JI; ++j) {
    const int t1 = 2 * j + 1, t2 = 2 * j + 2, t3 = 2 * j + 3;
    const bool g2 = (t2 < T), g3 = (t3 < T);
    // phases 1-4: consume tile 2j (buf0)
    PHASE(0, 0, 1, { STAGE_A(0, t1, 1); }, {});
    PHASE(0, 1, 0, { STAGE_A(1, t1, 1); }, {});
    PHASE(0, 2, 0, { if (g2) STAGE_B(0, t2, 0); }, {});
    PHASE(0, 3, 0, { if (g2) STAGE_B(1, t2, 0); },
          { if (g2) { asm volatile("s_waitcnt vmcnt(4)" ::: "memory"); }
            else    { asm volatile("s_waitcnt vmcnt(0)" ::: "memory"); } });
    // phases 5-8: consume tile 2j+1 (buf1)
    PHASE(1, 0, 1, { if (g2) STAGE_A(0, t2, 0); }, {});
    PHASE(1, 1, 0, { if (g2) STAGE_A(1, t2, 0); }, {});
    PHASE(1, 2, 0, { if (g3) STAGE_B(0, t3, 1); }, {});
    PHASE(1, 3, 0, { if (g3) STAGE_B(1, t3, 1); },
          { if (j + 1 < JI) {
              if (g3) { asm volatile("s_waitcnt vmcnt(4)" ::: "memory"); }
              else    { asm volatile("s_waitcnt vmcnt(0)" ::: "memory"); } } });
  }

#undef PHASE
#undef READ_BFR
#undef STAGE_A
#undef STAGE_B

  // ---------- GLU epilogue: stage bf16 [256][136] in LDS, coalesced write ----------
  // All async16 retired (last-iter ph4 drains vmcnt(0)); all LDS reads done (ph8 barrier).
  #pragma unroll
  for (int ni = 0; ni < 4; ++ni) {
    int lc = wn + ni * 16 + l16;
    int gi = (bn + lc) >> 1;
    float bv = bias[(l16 & 1) ? 4096 + gi : gi];
    #pragma unroll
    for (int mi = 0; mi < 8; ++mi) {
      #pragma unroll
      for (int r = 0; r < 4; ++r) {
        float v = acc[mi][ni][r] + bv;
        float p = __shfl_xor(v, 1);
        if ((l16 & 1) == 0) {
          int lr = wm + mi * 16 + quad * 4 + r;
          float g = (v / (1.f + __expf(-v))) * p;
          smem[lr * 136 + (lc >> 1)] = f2b(g);
        }
      }
    }
  }
  __syncthreads();
  {
    int lr = tid >> 1, half = (tid & 1) * 64;
    unsigned short* dst = out + (size_t)(bm + lr) * (N >> 1) + (bn >> 1) + half;
    const unsigned short* src = smem + lr * 136 + half;
    #pragma unroll
    for (int j = 0; j < 8; ++j)
      ((uint4*)dst)[j] = *(const uint4*)(src + j * 8);
  }
}

// ---------------- flash attention (S^T, Q-tile 128, K-tile 64, 8 waves) ----------------
// Round-6 dbuf (1 barrier/K-tile) + round-7 T13/T5/T17 kept (all null but free).

__global__ __launch_bounds__(512, 1) void attn_kernel(
    const unsigned short* __restrict__ q, const unsigned short* __restrict__ k,
    const unsigned short* __restrict__ vt, const int* __restrict__ amask,
    unsigned short* __restrict__ o) {
  const int bh = blockIdx.x;
  const int b = bh >> 4, h = bh & 15;
  const int qt = blockIdx.y;
  const int tid = threadIdx.x;
  const int wave = tid >> 6, lane = tid & 63;
  const int quad = lane >> 4, l16 = lane & 15;
  const int h7 = l16 & 7;
  const int kc0 = (quad ^ h7) * 8;
  const int kc1 = ((quad + 4) ^ h7) * 8;

  const unsigned short* qb = q  + (size_t)bh * 2048 * 64;
  const unsigned short* kb = k  + (size_t)bh * 2048 * 64;
  const unsigned short* vb = vt + (size_t)bh * 64 * 2048;

  __shared__ __align__(16) unsigned short Ks[2][64 * 64];   // 2x 8 KB, chunk-swizzled
  __shared__ __align__(16) unsigned short Vs[2][64 * 64];   // 2x 8 KB, chunk-swizzled
  __shared__ __align__(16) unsigned short Ps[8 * 16 * 72];  // per-wave P / epilogue stage (18 KB)
  __shared__ float biasf[2][64];

  unsigned short* PsW = Ps + wave * 1152;

  const int qrow = qt * 128 + wave * 16 + l16;
  bf16x8 qa0 = *reinterpret_cast<const bf16x8*>(&qb[(size_t)qrow * 64 + quad * 8]);
  bf16x8 qa1 = *reinterpret_cast<const bf16x8*>(&qb[(size_t)qrow * 64 + 32 + quad * 8]);

  f32x4 oacc[4] = {};
  float mrow = -30000.f, lrow = 0.f;

  // prefetch tile 0: 512 threads x 16B = one 8KB tile each for K and V
  uint4 kpre, vpre;
  {
    int key = tid >> 3, dl = (tid & 7) ^ (key & 7);
    kpre = *(const uint4*)(kb + key * 64 + dl * 8);
    int d = tid >> 3, kl = (tid & 7) ^ (d & 7);
    vpre = *(const uint4*)(vb + (size_t)d * 2048 + kl * 8);
  }
  int mv = (tid < 64) ? amask[b * 2048 + tid] : 0;

  for (int kt = 0; kt < 32; ++kt) {
    const int cb = kt & 1;
    // store tile kt (in regs) into buf[cb]; overlaps previous tile's compute tail
    ((uint4*)Ks[cb])[tid] = kpre;
    ((uint4*)Vs[cb])[tid] = vpre;
    if (tid < 64) biasf[cb][tid] = mv ? 0.f : -30000.f;
    __syncthreads();   // the ONE barrier: publishes tile-kt stores; prior reads of buf[cb] done

    if (kt + 1 < 32) {   // prefetch next tile during compute
      int key = tid >> 3, dl = (tid & 7) ^ (key & 7);
      kpre = *(const uint4*)(kb + (size_t)(kt + 1) * 4096 + key * 64 + dl * 8);
      int d = tid >> 3, kl = (tid & 7) ^ (d & 7);
      vpre = *(const uint4*)(vb + (size_t)d * 2048 + (kt + 1) * 64 + kl * 8);
      mv = (tid < 64) ? amask[b * 2048 + (kt + 1) * 64 + tid] : 0;
    }

    // S^T: lane holds S[q=l16][key=nt*16+quad*4+r]
    f32x4 st[4];
    __builtin_amdgcn_s_setprio(1);
    #pragma unroll
    for (int nt = 0; nt < 4; ++nt) {
      bf16x8 ka0 = *reinterpret_cast<const bf16x8*>(&Ks[cb][(nt * 16 + l16) * 64 + kc0]);
      bf16x8 ka1 = *reinterpret_cast<const bf16x8*>(&Ks[cb][(nt * 16 + l16) * 64 + kc1]);
      f32x4 bv = *reinterpret_cast<const f32x4*>(&biasf[cb][nt * 16 + quad * 4]);
      f32x4 z = {};
      z = __builtin_amdgcn_mfma_f32_16x16x32_bf16(ka0, qa0, z, 0, 0, 0);
      z = __builtin_amdgcn_mfma_f32_16x16x32_bf16(ka1, qa1, z, 0, 0, 0);
      st[nt] = z + bv;
    }
    __builtin_amdgcn_s_setprio(0);

    // row max via pairwise tree (seeds v_max3/v_max fusion)
    float m01 = fmaxf(fmaxf(st[0][0], st[0][1]), fmaxf(st[0][2], st[0][3]));
    float m23 = fmaxf(fmaxf(st[1][0], st[1][1]), fmaxf(st[1][2], st[1][3]));
    float m45 = fmaxf(fmaxf(st[2][0], st[2][1]), fmaxf(st[2][2], st[2][3]));
    float m67 = fmaxf(fmaxf(st[3][0], st[3][1]), fmaxf(st[3][2], st[3][3]));
    float tm = fmaxf(fmaxf(m01, m23), fmaxf(m45, m67));
    tm = fmaxf(tm, __shfl_xor(tm, 16));
    tm = fmaxf(tm, __shfl_xor(tm, 32));

    // T13 defer-max: skip rescale when no row in the wave grew past mrow+8
    const bool defer = __all(tm <= mrow + 8.f);
    if (!defer) {
      float mnew = fmaxf(mrow, tm);
      float alpha = __expf(mrow - mnew);
      mrow = mnew;
      float a0 = __shfl(alpha, quad * 4 + 0);
      float a1 = __shfl(alpha, quad * 4 + 1);
      float a2 = __shfl(alpha, quad * 4 + 2);
      float a3 = __shfl(alpha, quad * 4 + 3);
      #pragma unroll
      for (int dt = 0; dt < 4; ++dt) {
        oacc[dt][0] *= a0; oacc[dt][1] *= a1; oacc[dt][2] *= a2; oacc[dt][3] *= a3;
      }
      lrow *= alpha;
    }

    float rs = 0.f;
    #pragma unroll
    for (int nt = 0; nt < 4; ++nt) {
      float p0 = __expf(st[nt][0] - mrow);
      float p1 = __expf(st[nt][1] - mrow);
      float p2 = __expf(st[nt][2] - mrow);
      float p3 = __expf(st[nt][3] - mrow);
      rs += (p0 + p1) + (p2 + p3);
      uint2 w;
      w.x = packtrunc(p0, p1);
      w.y = packtrunc(p2, p3);
      *(uint2*)&PsW[l16 * 72 + nt * 16 + quad * 4] = w;
    }
    rs += __shfl_xor(rs, 16);
    rs += __shfl_xor(rs, 32);
    lrow += rs;

    // PV: A = P rows (per-wave LDS), B = V^T rows
    bf16x8 pa0 = *reinterpret_cast<const bf16x8*>(&PsW[l16 * 72 + quad * 8]);
    bf16x8 pa1 = *reinterpret_cast<const bf16x8*>(&PsW[l16 * 72 + 32 + quad * 8]);
    __builtin_amdgcn_s_setprio(1);
    #pragma unroll
    for (int dt = 0; dt < 4; ++dt) {
      bf16x8 vb0 = *reinterpret_cast<const bf16x8*>(&Vs[cb][(dt * 16 + l16) * 64 + kc0]);
      bf16x8 vb1 = *reinterpret_cast<const bf16x8*>(&Vs[cb][(dt * 16 + l16) * 64 + kc1]);
      oacc[dt] = __builtin_amdgcn_mfma_f32_16x16x32_bf16(pa0, vb0, oacc[dt], 0, 0, 0);
      oacc[dt] = __builtin_amdgcn_mfma_f32_16x16x32_bf16(pa1, vb1, oacc[dt], 0, 0, 0);
    }
    __builtin_amdgcn_s_setprio(0);
  }

  // epilogue: normalize, stage all 128 rows in Ps, coalesced writes
  float invl = lrow > 0.f ? 1.f / lrow : 0.f;
  float i0 = __shfl(invl, quad * 4 + 0);
  float i1 = __shfl(invl, quad * 4 + 1);
  float i2 = __shfl(invl, quad * 4 + 2);
  float i3 = __shfl(invl, quad * 4 + 3);
  __syncthreads();
  #pragma unroll
  for (int dt = 0; dt < 4; ++dt) {
    int lr = wave * 16 + quad * 4;
    Ps[(lr + 0) * 72 + dt * 16 + l16] = f2b(oacc[dt][0] * i0);
    Ps[(lr + 1) * 72 + dt * 16 + l16] = f2b(oacc[dt][1] * i1);
    Ps[(lr + 2) * 72 + dt * 16 + l16] = f2b(oacc[dt][2] * i2);
    Ps[(lr + 3) * 72 + dt * 16 + l16] = f2b(oacc[dt][3] * i3);
  }
  __syncthreads();
  {
    int lr = tid >> 2, cb2 = (tid & 3) * 16;
    int n = qt * 128 + lr;
    unsigned short* dst = o + ((size_t)(b * 2048 + n)) * 1024 + h * 64 + cb2;
    const unsigned short* src = Ps + lr * 72 + cb2;
    ((uint4*)dst)[0] = *(const uint4*)(src);
    ((uint4*)dst)[1] = *(const uint4*)(src + 8);
  }
}

// ---------------- launch ----------------

extern "C" void kernel_launch(void* const* d_in, const int* in_sizes, int n_in,
                              void* d_out, int out_size, void* d_ws, size_t ws_size,
                              hipStream_t stream) {
  const float* x       = (const float*)d_in[0];
  const float* c       = (const float*)d_in[1];
  const int*   amask   = (const int*)d_in[2];
  const float* norm_w  = (const float*)d_in[3];
  const float* scale_w = (const float*)d_in[4];
  const float* scale_b = (const float*)d_in[5];
  const float* shift_w = (const float*)d_in[6];
  const float* shift_b = (const float*)d_in[7];
  const float* qkv_w   = (const float*)d_in[8];
  const float* proj_w  = (const float*)d_in[9];
  const float* proj_b  = (const float*)d_in[10];
  const float* mlp_w1  = (const float*)d_in[11];
  const float* mlp_b1  = (const float*)d_in[12];
  const float* mlp_w2  = (const float*)d_in[13];
  const float* mlp_b2  = (const float*)d_in[14];

  char* ws = (char*)d_ws;
  unsigned short* wqkv  = (unsigned short*)(ws + 0);
  unsigned short* wproj = (unsigned short*)(ws + 6291456);
  unsigned short* wmlp1 = (unsigned short*)(ws + 8388608);   // interleaved gate/up rows
  unsigned short* wmlp2 = (unsigned short*)(ws + 25165824);
  float* scale_o        = (float*)(ws + 33554432);
  float* shift_o        = (float*)(ws + 33562624);
  unsigned short* hbuf  = (unsigned short*)(ws + 33570816);
  unsigned short* qbuf  = (unsigned short*)(ws + 41959424);
  unsigned short* kbuf  = (unsigned short*)(ws + 50348032);
  unsigned short* vbuf  = (unsigned short*)(ws + 58736640);
  unsigned short* abuf  = (unsigned short*)(ws + 67125248);
  unsigned short* gbuf  = qbuf;
  float* x1             = (float*)(ws + 75513856);

  // fused: weight cast (16384 blocks) + conditioning (32 blocks) in one launch
  prep_kernel<<<16416, 256, 0, stream>>>(qkv_w, proj_w, mlp_w1, mlp_w2,
                                         wqkv, wproj, wmlp1, wmlp2,
                                         c, scale_w, scale_b, shift_w, shift_b,
                                         scale_o, shift_o);

  adaln_kernel<<<4096, 256, 0, stream>>>(x, norm_w, scale_o, shift_o, hbuf);

  gemm_k<1, 128><<<dim3(24, 32), 256, 0, stream>>>(hbuf, wqkv, nullptr, nullptr,
                                                   qbuf, kbuf, vbuf, 4096, 3072, 1024);

  attn_kernel<<<dim3(32, 16), 512, 0, stream>>>(qbuf, kbuf, vbuf, amask, abuf);

  gemm_k<0, 64><<<dim3(8, 64), 256, 0, stream>>>(abuf, wproj, proj_b, x,
                                                 x1, nullptr, nullptr, 4096, 1024, 1024);

  adaln_kernel<<<4096, 256, 0, stream>>>(x1, norm_w, scale_o, shift_o, hbuf);

  gemm256_glu<<<dim3(32, 16), 512, 0, stream>>>(hbuf, wmlp1, mlp_b1, gbuf, 4096, 8192, 1024);

  gemm_k<0, 64><<<dim3(8, 64), 256, 0, stream>>>(gbuf, wmlp2, mlp_b2, x1,
                                                 d_out, nullptr, nullptr, 4096, 1024, 4096);

  (void)in_sizes; (void)n_in; (void)out_size; (void)ws_size;
}